// Round 9
// baseline (250.549 us; speedup 1.0000x reference)
//
#include <hip/hip_runtime.h>
#include <math.h>

#define DIM 16
#define HID 32

typedef float  f32x4  __attribute__((ext_vector_type(4)));
typedef float  v2f    __attribute__((ext_vector_type(2)));
typedef short  bf16x8 __attribute__((ext_vector_type(8)));

// f32 -> bf16 RNE via integer ops. Pure C (no inline asm): every instruction
// is visible to the compiler's hazard model. (The asm v_cvt_pk_bf16_f32
// variant is implicated -- but not proven -- in the R4/R6/R7 loop NaNs;
// packbf passed the harness in round 0.)
__device__ inline unsigned short f2bf(float f) {
    union { float f; unsigned u; } v; v.f = f;
    unsigned r = v.u + 0x7fffu + ((v.u >> 16) & 1u);   // RNE
    return (unsigned short)(r >> 16);
}
__device__ inline unsigned packbf(float lo, float hi) {
    return (unsigned)f2bf(lo) | ((unsigned)f2bf(hi) << 16);
}

// Packed-pair GELU, exact erf via A&S 7.1.26 (|err|<1.5e-7), sign-free:
// gelu(h) = 0.5h + 0.5|h| * erf(|h|/sqrt2);  e^{-z^2} via one v_exp2 each.
__device__ inline v2f gelu2(v2f h) {
    v2f hh  = h * (v2f){0.5f, 0.5f};                                   // 0.5h
    v2f ahh = __builtin_elementwise_abs(hh);                           // 0.5|h|
    v2f az  = ahh * (v2f){1.41421356237309505f, 1.41421356237309505f}; // |z|
    v2f den = __builtin_elementwise_fma(az, (v2f){0.3275911f, 0.3275911f},
                                        (v2f){1.0f, 1.0f});
    v2f t   = (v2f){__builtin_amdgcn_rcpf(den.x), __builtin_amdgcn_rcpf(den.y)};
    v2f h2  = h * h;
    v2f ex  = h2 * (v2f){-0.721347520444482f, -0.721347520444482f};    // -z^2*log2e
    v2f e   = (v2f){__builtin_amdgcn_exp2f(ex.x), __builtin_amdgcn_exp2f(ex.y)};
    v2f p   = __builtin_elementwise_fma(t, (v2f){1.061405429f, 1.061405429f},
                                        (v2f){-1.453152027f, -1.453152027f});
    p = __builtin_elementwise_fma(t, p, (v2f){1.421413741f, 1.421413741f});
    p = __builtin_elementwise_fma(t, p, (v2f){-0.284496736f, -0.284496736f});
    p = __builtin_elementwise_fma(t, p, (v2f){0.254829592f, 0.254829592f});
    p = p * t;
    v2f erfa = __builtin_elementwise_fma(-p, e, (v2f){1.0f, 1.0f});    // erf(|z|)
    return __builtin_elementwise_fma(ahh, erfa, hh);
}

// Straight-line x4 chunk unroll -- NO loop, NO inline asm. Structure is the
// round-3-verified kernel with tiles-per-wave raised 4 -> 16 (256 contiguous
// rows per wave): all 16 dwordx4 x-loads issued up front (deep MLP window),
// weight fragments amortized over 4x the rows, grid 8192 -> 2048 blocks
// (2 occupancy rounds at 16 waves/CU instead of 4 at 32). Per-tile body is
// byte-identical to round 3 except packbf replaces asm cvt_pk.
// Lane (q = lane>>4, c = lane&15) owns dims/hids 4q..4q+3 of row t*16+c in
// every stage; B-fragment k-slots 8q..8q+7 fed by a chosen K-permutation:
//   W1: dim 4q+j -> k=8q+j (j<4), upper half zero-padded.
//   W2: hid(k=8q+j) = j<4 ? 4q+j : 16+4q+(j-4)  (bijection, no padding).
// D layout (col=c, row=4q+r) == residual == store layout. No LDS/barriers.
__global__ __launch_bounds__(256, 4) void fused_ln_mlp_mfma(
    const float* __restrict__ x,
    const float* __restrict__ ln_w,
    const float* __restrict__ ln_b,
    const float* __restrict__ w1,   // [HID][DIM] row-major
    const float* __restrict__ b1,   // [HID]
    const float* __restrict__ w2,   // [DIM][HID] row-major
    const float* __restrict__ b2,   // [DIM]
    float* __restrict__ out,
    int nrows)
{
    const int tid  = threadIdx.x;
    const int lane = tid & 63;
    const int wave = tid >> 6;
    const int q    = lane >> 4;     // quad index 0..3
    const int c    = lane & 15;     // within-16 index

    // 256 contiguous rows per wave, 1024 per block.
    const int wavebase = (blockIdx.x * 4 + wave) * 256;
    if (wavebase >= nrows) return;   // uniform per wave (exact division normally)

    // ---- per-lane weight fragments (amortized over 256 rows) ----
    // W1 A-frag, hid-half t: A[row = hid 16t+c][k=8q+j] = w1[(16t+c)*DIM+4q+j]
    // for j<4, zero for j>=4 (k-permuted zero padding).
    bf16x8 aW1[2];
    #pragma unroll
    for (int t = 0; t < 2; t++) {
        bf16x8 f = {0, 0, 0, 0, 0, 0, 0, 0};
        const float* wp = w1 + (16 * t + c) * DIM + 4 * q;
        #pragma unroll
        for (int j = 0; j < 4; j++)
            ((unsigned short*)&f)[j] = f2bf(wp[j]);
        aW1[t] = f;
    }
    // W2 A-frag: A[row = dim c][k=8q+j] = w2[c*HID + hid(q,j)],
    // hid(q,j) = j<4 ? 4q+j : 16+4q+(j-4).
    bf16x8 aW2;
    {
        const float* wp = w2 + c * HID;
        #pragma unroll
        for (int j = 0; j < 8; j++) {
            int hid = (j < 4) ? (4 * q + j) : (16 + 4 * q + (j - 4));
            ((unsigned short*)&aW2)[j] = f2bf(wp[hid]);
        }
    }
    const f32x4 b1q0 = *(const f32x4*)(b1 + 4 * q);        // hid 4q+r
    const f32x4 b1q1 = *(const f32x4*)(b1 + 16 + 4 * q);   // hid 16+4q+r
    const f32x4 b2q  = *(const f32x4*)(b2 + 4 * q);        // dim 4q+r
    const f32x4 lnw4 = *(const f32x4*)(ln_w + 4 * q);
    const f32x4 lnb4 = *(const f32x4*)(ln_b + 4 * q);

    // ---- all 16 tile loads issued up front (fragment == residual layout) ----
    f32x4 xv[16];
    #pragma unroll
    for (int t = 0; t < 16; t++)
        xv[t] = *(const f32x4*)(x + (size_t)(wavebase + t * 16 + c) * DIM + 4 * q);

    // ---- 16 independent straight-line tile bodies (round-3 verified) ----
    #pragma unroll
    for (int t = 0; t < 16; t++) {
        const f32x4 v = xv[t];

        // LN stats: lane-local (s, ss), 4-lane butterfly over the q bits.
        float s  = (v.x + v.y) + (v.z + v.w);
        float ss = fmaf(v.x, v.x, fmaf(v.y, v.y, fmaf(v.z, v.z, v.w * v.w)));
        s  += __shfl_xor(s, 16);  ss += __shfl_xor(ss, 16);
        s  += __shfl_xor(s, 32);  ss += __shfl_xor(ss, 32);
        float mu  = s * (1.0f / DIM);
        float var = fmaf(-mu, mu, ss * (1.0f / DIM));
        float a   = __builtin_amdgcn_rsqf(var + 1e-5f);

        f32x4 aw  = lnw4 * a;
        f32x4 muv = {mu, mu, mu, mu};
        f32x4 off = __builtin_elementwise_fma(-muv, aw, lnb4);
        f32x4 xn  = __builtin_elementwise_fma(v, aw, off);

        // B-frag for W1: k=8q..8q+3 = dims 4q..4q+3, k=8q+4..8q+7 = 0.
        union { unsigned u[4]; bf16x8 f; } bX;
        bX.u[0] = packbf(xn.x, xn.y);
        bX.u[1] = packbf(xn.z, xn.w);
        bX.u[2] = 0u;
        bX.u[3] = 0u;

        // ---- W1 (Hᵀ = W1·Xnᵀ), two hid halves, verified K=32 MFMA ----
        const f32x4 z = {0.f, 0.f, 0.f, 0.f};
        f32x4 h0 = __builtin_amdgcn_mfma_f32_16x16x32_bf16(aW1[0], bX.f, z, 0, 0, 0) + b1q0;
        f32x4 h1 = __builtin_amdgcn_mfma_f32_16x16x32_bf16(aW1[1], bX.f, z, 0, 0, 0) + b1q1;

        // ---- packed GELU -> B-frag for W2 (k-permuted, lane-local) ----
        v2f g0 = gelu2((v2f){h0.x, h0.y});    // hid 4q+0,1      -> k 8q+0,1
        v2f g1 = gelu2((v2f){h0.z, h0.w});    // hid 4q+2,3      -> k 8q+2,3
        v2f g2 = gelu2((v2f){h1.x, h1.y});    // hid 16+4q+0,1   -> k 8q+4,5
        v2f g3 = gelu2((v2f){h1.z, h1.w});    // hid 16+4q+2,3   -> k 8q+6,7
        union { unsigned u[4]; bf16x8 f; } bP;
        bP.u[0] = packbf(g0.x, g0.y);
        bP.u[1] = packbf(g1.x, g1.y);
        bP.u[2] = packbf(g2.x, g2.y);
        bP.u[3] = packbf(g3.x, g3.y);

        // ---- W2 (Yᵀ = W2·Pᵀ): ONE K=32 MFMA covers all 32 hids ----
        f32x4 acc = __builtin_amdgcn_mfma_f32_16x16x32_bf16(aW2, bP.f, z, 0, 0, 0);

        // ---- epilogue: + b2 + residual, coalesced nt dwordx4 store ----
        f32x4 o = acc + b2q + v;
        size_t base = (size_t)(wavebase + t * 16 + c) * DIM + 4 * q;
        __builtin_nontemporal_store(o, (f32x4*)(out + base));
    }
}

extern "C" void kernel_launch(void* const* d_in, const int* in_sizes, int n_in,
                              void* d_out, int out_size, void* d_ws, size_t ws_size,
                              hipStream_t stream) {
    const float* x    = (const float*)d_in[0];
    const float* ln_w = (const float*)d_in[1];
    const float* ln_b = (const float*)d_in[2];
    const float* w1   = (const float*)d_in[3];
    const float* b1   = (const float*)d_in[4];
    const float* w2   = (const float*)d_in[5];
    const float* b2   = (const float*)d_in[6];
    float* out = (float*)d_out;

    int nrows = in_sizes[0] / DIM;            // 2,097,152
    int rows_per_block = 1024;                // 4 waves x 256 rows
    int grid = (nrows + rows_per_block - 1) / rows_per_block;   // 2048

    fused_ln_mlp_mfma<<<grid, 256, 0, stream>>>(
        x, ln_w, ln_b, w1, b1, w2, b2, out, nrows);
}

// Round 10
// 248.263 us; speedup vs baseline: 1.0092x; 1.0092x over previous
//
#include <hip/hip_runtime.h>
#include <math.h>

#define DIM 16
#define HID 32

typedef float  f32x4  __attribute__((ext_vector_type(4)));
typedef float  v2f    __attribute__((ext_vector_type(2)));
typedef short  bf16x8 __attribute__((ext_vector_type(8)));

// f32 -> bf16 RNE via integer ops. Pure C (no inline asm): fully visible to
// the compiler's hazard model (asm cvt_pk implicated in the R4/R6/R7 NaNs).
__device__ inline unsigned short f2bf(float f) {
    union { float f; unsigned u; } v; v.f = f;
    unsigned r = v.u + 0x7fffu + ((v.u >> 16) & 1u);   // RNE
    return (unsigned short)(r >> 16);
}
__device__ inline unsigned packbf(float lo, float hi) {
    return (unsigned)f2bf(lo) | ((unsigned)f2bf(hi) << 16);
}

// tanh-form GELU (PyTorch approximate='tanh'; |Delta vs exact erf| <~3e-4,
// threshold is 0.114): gelu(x) = x * sigmoid(2*c0*(x + c1 x^3)).
// Computed as x / (1 + exp2(-arg)), arg = x*(K0 + K1 x^2),
// K0 = 2*log2(e)*c0, K1 = K0*c1. NaN-safe at both extremes:
//   x -> +inf: exp2(-arg) -> 0,  r -> 1,  out -> x    (correct limit)
//   x -> -inf: exp2(-arg) -> inf, r -> 0, out -> 0    (correct limit)
__device__ inline v2f gelu2(v2f h) {
    const v2f nK1 = {-0.1029435f, -0.1029435f};   // -K0*0.044715
    const v2f nK0 = {-2.3022082f, -2.3022082f};   // -2*log2e*0.7978845608
    v2f s2   = h * h;
    v2f innn = __builtin_elementwise_fma(s2, nK1, nK0);
    v2f argn = h * innn;                          // = -arg
    v2f e2   = {__builtin_amdgcn_exp2f(argn.x), __builtin_amdgcn_exp2f(argn.y)};
    v2f den  = e2 + (v2f){1.0f, 1.0f};
    v2f r    = {__builtin_amdgcn_rcpf(den.x), __builtin_amdgcn_rcpf(den.y)};
    return h * r;
}

// R9 structure (passed, absmax 0.03125) with the load window actually
// enforced: 16 tiles (256 rows) per wave, all 16 dwordx4 x-loads issued
// BEFORE compute, pinned by sched_barrier(0) (instruction-motion fence;
// R9's counters proved the compiler otherwise sinks them: VGPR was 40).
// launch_bounds(256,2) raises the VGPR cap so xv[16] lives in registers.
// Per-tile body: LN (4-lane shfl reduce) -> bf16 B-frag (k-permuted:
// dim 4q+j -> k 8q+j, upper half zero) -> 2x K=32 MFMA (W1 halves) ->
// packed GELU -> B-frag (hid(k=8q+j) = j<4 ? 4q+j : 16+4q+j-4) -> ONE
// K=32 MFMA (W2) -> +b2 +residual -> nt dwordx4 store.
// D layout (col=c, row=4q+r) == residual == store layout. No LDS/barriers.
__global__ __launch_bounds__(256, 2) void fused_ln_mlp_mfma(
    const float* __restrict__ x,
    const float* __restrict__ ln_w,
    const float* __restrict__ ln_b,
    const float* __restrict__ w1,   // [HID][DIM] row-major
    const float* __restrict__ b1,   // [HID]
    const float* __restrict__ w2,   // [DIM][HID] row-major
    const float* __restrict__ b2,   // [DIM]
    float* __restrict__ out,
    int nrows)
{
    const int tid  = threadIdx.x;
    const int lane = tid & 63;
    const int wave = tid >> 6;
    const int q    = lane >> 4;     // quad index 0..3
    const int c    = lane & 15;     // within-16 index

    // 256 contiguous rows per wave, 1024 per block.
    const int wavebase = (blockIdx.x * 4 + wave) * 256;
    if (wavebase >= nrows) return;

    // ---- per-lane weight fragments (amortized over 256 rows) ----
    // W1 A-frag, hid-half t: A[row = hid 16t+c][k=8q+j] = w1[(16t+c)*DIM+4q+j]
    // for j<4, zero for j>=4 (k-permuted zero padding).
    bf16x8 aW1[2];
    #pragma unroll
    for (int t = 0; t < 2; t++) {
        bf16x8 f = {0, 0, 0, 0, 0, 0, 0, 0};
        const float* wp = w1 + (16 * t + c) * DIM + 4 * q;
        #pragma unroll
        for (int j = 0; j < 4; j++)
            ((unsigned short*)&f)[j] = f2bf(wp[j]);
        aW1[t] = f;
    }
    // W2 A-frag: A[row = dim c][k=8q+j] = w2[c*HID + hid(q,j)],
    // hid(q,j) = j<4 ? 4q+j : 16+4q+(j-4).
    bf16x8 aW2;
    {
        const float* wp = w2 + c * HID;
        #pragma unroll
        for (int j = 0; j < 8; j++) {
            int hid = (j < 4) ? (4 * q + j) : (16 + 4 * q + (j - 4));
            ((unsigned short*)&aW2)[j] = f2bf(wp[hid]);
        }
    }
    const f32x4 b1q0 = *(const f32x4*)(b1 + 4 * q);        // hid 4q+r
    const f32x4 b1q1 = *(const f32x4*)(b1 + 16 + 4 * q);   // hid 16+4q+r
    const f32x4 b2q  = *(const f32x4*)(b2 + 4 * q);        // dim 4q+r
    const f32x4 lnw4 = *(const f32x4*)(ln_w + 4 * q);
    const f32x4 lnb4 = *(const f32x4*)(ln_b + 4 * q);

    // ---- all 16 tile loads issued up front (fragment == residual layout) ----
    f32x4 xv[16];
    #pragma unroll
    for (int t = 0; t < 16; t++)
        xv[t] = *(const f32x4*)(x + (size_t)(wavebase + t * 16 + c) * DIM + 4 * q);

    // Scheduling fence: nothing (in particular the 16 loads above) may be
    // moved across this point. Pure scheduler directive — no semantic effect.
    __builtin_amdgcn_sched_barrier(0);

    // ---- 16 straight-line tile bodies ----
    #pragma unroll
    for (int t = 0; t < 16; t++) {
        const f32x4 v = xv[t];

        // LN stats: lane-local (s, ss), 4-lane butterfly over the q bits.
        float s  = (v.x + v.y) + (v.z + v.w);
        float ss = fmaf(v.x, v.x, fmaf(v.y, v.y, fmaf(v.z, v.z, v.w * v.w)));
        s  += __shfl_xor(s, 16);  ss += __shfl_xor(ss, 16);
        s  += __shfl_xor(s, 32);  ss += __shfl_xor(ss, 32);
        float mu  = s * (1.0f / DIM);
        float var = fmaf(-mu, mu, ss * (1.0f / DIM));
        float a   = __builtin_amdgcn_rsqf(var + 1e-5f);

        f32x4 aw  = lnw4 * a;
        f32x4 muv = {mu, mu, mu, mu};
        f32x4 off = __builtin_elementwise_fma(-muv, aw, lnb4);
        f32x4 xn  = __builtin_elementwise_fma(v, aw, off);

        // B-frag for W1: k=8q..8q+3 = dims 4q..4q+3, k=8q+4..8q+7 = 0.
        union { unsigned u[4]; bf16x8 f; } bX;
        bX.u[0] = packbf(xn.x, xn.y);
        bX.u[1] = packbf(xn.z, xn.w);
        bX.u[2] = 0u;
        bX.u[3] = 0u;

        // ---- W1 (Hᵀ = W1·Xnᵀ), two hid halves, verified K=32 MFMA ----
        const f32x4 z = {0.f, 0.f, 0.f, 0.f};
        f32x4 h0 = __builtin_amdgcn_mfma_f32_16x16x32_bf16(aW1[0], bX.f, z, 0, 0, 0) + b1q0;
        f32x4 h1 = __builtin_amdgcn_mfma_f32_16x16x32_bf16(aW1[1], bX.f, z, 0, 0, 0) + b1q1;

        // ---- packed GELU -> B-frag for W2 (k-permuted, lane-local) ----
        v2f g0 = gelu2((v2f){h0.x, h0.y});    // hid 4q+0,1      -> k 8q+0,1
        v2f g1 = gelu2((v2f){h0.z, h0.w});    // hid 4q+2,3      -> k 8q+2,3
        v2f g2 = gelu2((v2f){h1.x, h1.y});    // hid 16+4q+0,1   -> k 8q+4,5
        v2f g3 = gelu2((v2f){h1.z, h1.w});    // hid 16+4q+2,3   -> k 8q+6,7
        union { unsigned u[4]; bf16x8 f; } bP;
        bP.u[0] = packbf(g0.x, g0.y);
        bP.u[1] = packbf(g1.x, g1.y);
        bP.u[2] = packbf(g2.x, g2.y);
        bP.u[3] = packbf(g3.x, g3.y);

        // ---- W2 (Yᵀ = W2·Pᵀ): ONE K=32 MFMA covers all 32 hids ----
        f32x4 acc = __builtin_amdgcn_mfma_f32_16x16x32_bf16(aW2, bP.f, z, 0, 0, 0);

        // ---- epilogue: + b2 + residual, coalesced nt dwordx4 store ----
        f32x4 o = acc + b2q + v;
        size_t base = (size_t)(wavebase + t * 16 + c) * DIM + 4 * q;
        __builtin_nontemporal_store(o, (f32x4*)(out + base));
    }
}

extern "C" void kernel_launch(void* const* d_in, const int* in_sizes, int n_in,
                              void* d_out, int out_size, void* d_ws, size_t ws_size,
                              hipStream_t stream) {
    const float* x    = (const float*)d_in[0];
    const float* ln_w = (const float*)d_in[1];
    const float* ln_b = (const float*)d_in[2];
    const float* w1   = (const float*)d_in[3];
    const float* b1   = (const float*)d_in[4];
    const float* w2   = (const float*)d_in[5];
    const float* b2   = (const float*)d_in[6];
    float* out = (float*)d_out;

    int nrows = in_sizes[0] / DIM;            // 2,097,152
    int rows_per_block = 1024;                // 4 waves x 256 rows
    int grid = (nrows + rows_per_block - 1) / rows_per_block;   // 2048

    fused_ln_mlp_mfma<<<grid, 256, 0, stream>>>(
        x, ln_w, ln_b, w1, b1, w2, b2, out, nrows);
}

// Round 11
// 242.135 us; speedup vs baseline: 1.0348x; 1.0253x over previous
//
#include <hip/hip_runtime.h>
#include <math.h>

#define DIM 16
#define HID 32

typedef float  f32x4  __attribute__((ext_vector_type(4)));
typedef float  v2f    __attribute__((ext_vector_type(2)));
typedef short  bf16x8 __attribute__((ext_vector_type(8)));

// f32 -> bf16 RNE via integer ops. Pure C (no inline asm) — harness-verified.
__device__ inline unsigned short f2bf(float f) {
    union { float f; unsigned u; } v; v.f = f;
    unsigned r = v.u + 0x7fffu + ((v.u >> 16) & 1u);   // RNE
    return (unsigned short)(r >> 16);
}
__device__ inline unsigned packbf(float lo, float hi) {
    return (unsigned)f2bf(lo) | ((unsigned)f2bf(hi) << 16);
}

// tanh-form GELU (harness-verified in R10, absmax 0.03125 unchanged):
// gelu(x) = x * sigmoid(2*c0*(x + c1 x^3)) computed as x / (1 + exp2(-arg)).
// NaN-safe at both extremes (x->+inf: out->x; x->-inf: out->0).
__device__ inline v2f gelu2(v2f h) {
    const v2f nK1 = {-0.1029435f, -0.1029435f};   // -K0*0.044715
    const v2f nK0 = {-2.3022082f, -2.3022082f};   // -2*log2e*0.7978845608
    v2f s2   = h * h;
    v2f innn = __builtin_elementwise_fma(s2, nK1, nK0);
    v2f argn = h * innn;                          // = -arg
    v2f e2   = {__builtin_amdgcn_exp2f(argn.x), __builtin_amdgcn_exp2f(argn.y)};
    v2f den  = e2 + (v2f){1.0f, 1.0f};
    v2f r    = {__builtin_amdgcn_rcpf(den.x), __builtin_amdgcn_rcpf(den.y)};
    return h * r;
}

// Occupancy/depth middle point (R3 = 8 waves/SIMD x 4 loads; R10 = 2 x 8;
// here: 3 waves/SIMD x 8 loads). 4096 blocks, 128 rows per wave (8 tiles),
// launch_bounds(256,3) -> VGPR cap 85, enough to hold xv[8] (R9's cap 64
// forced load-sinking; R10's cap 128 cost occupancy). All 8 dwordx4 x-loads
// issued before compute, pinned by sched_barrier(0). Per-tile body is the
// round-3-verified pipeline: LN (4-lane shfl reduce) -> bf16 B-frag
// (k-permuted: dim 4q+j -> k 8q+j, upper half zero) -> 2x K=32 MFMA (W1
// halves) -> packed GELU -> B-frag (hid(k=8q+j) = j<4 ? 4q+j : 16+4q+j-4)
// -> ONE K=32 MFMA (W2) -> +b2 +residual -> nt dwordx4 store.
// D layout (col=c, row=4q+r) == residual == store layout. No LDS/barriers.
__global__ __launch_bounds__(256, 3) void fused_ln_mlp_mfma(
    const float* __restrict__ x,
    const float* __restrict__ ln_w,
    const float* __restrict__ ln_b,
    const float* __restrict__ w1,   // [HID][DIM] row-major
    const float* __restrict__ b1,   // [HID]
    const float* __restrict__ w2,   // [DIM][HID] row-major
    const float* __restrict__ b2,   // [DIM]
    float* __restrict__ out,
    int nrows)
{
    const int tid  = threadIdx.x;
    const int lane = tid & 63;
    const int wave = tid >> 6;
    const int q    = lane >> 4;     // quad index 0..3
    const int c    = lane & 15;     // within-16 index

    // 128 contiguous rows per wave, 512 per block.
    const int wavebase = (blockIdx.x * 4 + wave) * 128;
    if (wavebase >= nrows) return;

    // ---- per-lane weight fragments (amortized over 128 rows) ----
    // W1 A-frag, hid-half t: A[row = hid 16t+c][k=8q+j] = w1[(16t+c)*DIM+4q+j]
    // for j<4, zero for j>=4 (k-permuted zero padding).
    bf16x8 aW1[2];
    #pragma unroll
    for (int t = 0; t < 2; t++) {
        bf16x8 f = {0, 0, 0, 0, 0, 0, 0, 0};
        const float* wp = w1 + (16 * t + c) * DIM + 4 * q;
        #pragma unroll
        for (int j = 0; j < 4; j++)
            ((unsigned short*)&f)[j] = f2bf(wp[j]);
        aW1[t] = f;
    }
    // W2 A-frag: A[row = dim c][k=8q+j] = w2[c*HID + hid(q,j)],
    // hid(q,j) = j<4 ? 4q+j : 16+4q+(j-4).
    bf16x8 aW2;
    {
        const float* wp = w2 + c * HID;
        #pragma unroll
        for (int j = 0; j < 8; j++) {
            int hid = (j < 4) ? (4 * q + j) : (16 + 4 * q + (j - 4));
            ((unsigned short*)&aW2)[j] = f2bf(wp[hid]);
        }
    }
    const f32x4 b1q0 = *(const f32x4*)(b1 + 4 * q);        // hid 4q+r
    const f32x4 b1q1 = *(const f32x4*)(b1 + 16 + 4 * q);   // hid 16+4q+r
    const f32x4 b2q  = *(const f32x4*)(b2 + 4 * q);        // dim 4q+r
    const f32x4 lnw4 = *(const f32x4*)(ln_w + 4 * q);
    const f32x4 lnb4 = *(const f32x4*)(ln_b + 4 * q);

    // ---- all 8 tile loads issued up front (fragment == residual layout) ----
    f32x4 xv[8];
    #pragma unroll
    for (int t = 0; t < 8; t++)
        xv[t] = *(const f32x4*)(x + (size_t)(wavebase + t * 16 + c) * DIM + 4 * q);

    // Scheduling fence: the 8 loads above may not sink past this point.
    __builtin_amdgcn_sched_barrier(0);

    // ---- 8 straight-line tile bodies ----
    #pragma unroll
    for (int t = 0; t < 8; t++) {
        const f32x4 v = xv[t];

        // LN stats: lane-local (s, ss), 4-lane butterfly over the q bits.
        float s  = (v.x + v.y) + (v.z + v.w);
        float ss = fmaf(v.x, v.x, fmaf(v.y, v.y, fmaf(v.z, v.z, v.w * v.w)));
        s  += __shfl_xor(s, 16);  ss += __shfl_xor(ss, 16);
        s  += __shfl_xor(s, 32);  ss += __shfl_xor(ss, 32);
        float mu  = s * (1.0f / DIM);
        float var = fmaf(-mu, mu, ss * (1.0f / DIM));
        float a   = __builtin_amdgcn_rsqf(var + 1e-5f);

        f32x4 aw  = lnw4 * a;
        f32x4 muv = {mu, mu, mu, mu};
        f32x4 off = __builtin_elementwise_fma(-muv, aw, lnb4);
        f32x4 xn  = __builtin_elementwise_fma(v, aw, off);

        // B-frag for W1: k=8q..8q+3 = dims 4q..4q+3, k=8q+4..8q+7 = 0.
        union { unsigned u[4]; bf16x8 f; } bX;
        bX.u[0] = packbf(xn.x, xn.y);
        bX.u[1] = packbf(xn.z, xn.w);
        bX.u[2] = 0u;
        bX.u[3] = 0u;

        // ---- W1 (Hᵀ = W1·Xnᵀ), two hid halves, verified K=32 MFMA ----
        const f32x4 z = {0.f, 0.f, 0.f, 0.f};
        f32x4 h0 = __builtin_amdgcn_mfma_f32_16x16x32_bf16(aW1[0], bX.f, z, 0, 0, 0) + b1q0;
        f32x4 h1 = __builtin_amdgcn_mfma_f32_16x16x32_bf16(aW1[1], bX.f, z, 0, 0, 0) + b1q1;

        // ---- packed GELU -> B-frag for W2 (k-permuted, lane-local) ----
        v2f g0 = gelu2((v2f){h0.x, h0.y});    // hid 4q+0,1      -> k 8q+0,1
        v2f g1 = gelu2((v2f){h0.z, h0.w});    // hid 4q+2,3      -> k 8q+2,3
        v2f g2 = gelu2((v2f){h1.x, h1.y});    // hid 16+4q+0,1   -> k 8q+4,5
        v2f g3 = gelu2((v2f){h1.z, h1.w});    // hid 16+4q+2,3   -> k 8q+6,7
        union { unsigned u[4]; bf16x8 f; } bP;
        bP.u[0] = packbf(g0.x, g0.y);
        bP.u[1] = packbf(g1.x, g1.y);
        bP.u[2] = packbf(g2.x, g2.y);
        bP.u[3] = packbf(g3.x, g3.y);

        // ---- W2 (Yᵀ = W2·Pᵀ): ONE K=32 MFMA covers all 32 hids ----
        f32x4 acc = __builtin_amdgcn_mfma_f32_16x16x32_bf16(aW2, bP.f, z, 0, 0, 0);

        // ---- epilogue: + b2 + residual, coalesced nt dwordx4 store ----
        f32x4 o = acc + b2q + v;
        size_t base = (size_t)(wavebase + t * 16 + c) * DIM + 4 * q;
        __builtin_nontemporal_store(o, (f32x4*)(out + base));
    }
}

extern "C" void kernel_launch(void* const* d_in, const int* in_sizes, int n_in,
                              void* d_out, int out_size, void* d_ws, size_t ws_size,
                              hipStream_t stream) {
    const float* x    = (const float*)d_in[0];
    const float* ln_w = (const float*)d_in[1];
    const float* ln_b = (const float*)d_in[2];
    const float* w1   = (const float*)d_in[3];
    const float* b1   = (const float*)d_in[4];
    const float* w2   = (const float*)d_in[5];
    const float* b2   = (const float*)d_in[6];
    float* out = (float*)d_out;

    int nrows = in_sizes[0] / DIM;            // 2,097,152
    int rows_per_block = 512;                 // 4 waves x 128 rows
    int grid = (nrows + rows_per_block - 1) / rows_per_block;   // 4096

    fused_ln_mlp_mfma<<<grid, 256, 0, stream>>>(
        x, ln_w, ln_b, w1, b1, w2, b2, out, nrows);
}